// Round 2
// baseline (1025.338 us; speedup 1.0000x reference)
//
#include <hip/hip_runtime.h>
#include <hip/hip_bf16.h>

#define H_ 16
#define B_ 8
#define S_ 1024
#define D_ 1024
#define E_ 64
#define HB_ 128
#define LN_EPS 1e-5f

typedef unsigned short u16;
typedef __bf16 bf16x8 __attribute__((ext_vector_type(8)));
typedef u16 u16x8 __attribute__((ext_vector_type(8)));
typedef u16 u16x4 __attribute__((ext_vector_type(4)));
typedef float f32x4 __attribute__((ext_vector_type(4)));

#define MFMA16(a, b, c) __builtin_amdgcn_mfma_f32_16x16x32_bf16( \
    __builtin_bit_cast(bf16x8, (a)), __builtin_bit_cast(bf16x8, (b)), (c), 0, 0, 0)

__device__ __forceinline__ u16 f2bf(float x) {
  union { float f; unsigned u; } v; v.f = x;
  unsigned r = v.u + 0x7fffu + ((v.u >> 16) & 1u);
  return (u16)(r >> 16);
}

// ---- prep: W [H][D][E] f32 -> Wt [(h*64+e)][D] bf16 (scaled) ----
__global__ void k_transpose_w(const float* __restrict__ W, u16* __restrict__ Wt, float scale) {
  int tid = blockIdx.x * 256 + threadIdx.x;   // H*D*E = 1,048,576
  int e = tid & 63, d = (tid >> 6) & 1023, h = tid >> 16;
  Wt[(size_t)(h * 64 + e) * 1024 + d] = f2bf(W[tid] * scale);
}

// ---- prep: Wp [K][N] f32 -> Wpt [N][K] bf16 ----
__global__ void k_transpose_wp(const float* __restrict__ W, u16* __restrict__ Wt) {
  int tid = blockIdx.x * 256 + threadIdx.x;   // 1,048,576
  int n = tid & 1023, k = tid >> 10;
  Wt[(size_t)n * 1024 + k] = f2bf(W[tid]);
}

// ---- prep: X f32 -> bf16, 8 elems/thread ----
__global__ void k_convert(const float* __restrict__ X, u16* __restrict__ Y) {
  int i = (blockIdx.x * 256 + threadIdx.x) * 8;
  float4 a = *(const float4*)(X + i);
  float4 b = *(const float4*)(X + i + 4);
  u16x8 v;
  v[0] = f2bf(a.x); v[1] = f2bf(a.y); v[2] = f2bf(a.z); v[3] = f2bf(a.w);
  v[4] = f2bf(b.x); v[5] = f2bf(b.y); v[6] = f2bf(b.z); v[7] = f2bf(b.w);
  *(u16x8*)(Y + i) = v;
}

// ---- fused QKV GEMM: Xb[8192][1024] bf16 @ Wt -> Q/K [hb][s][64], V^T [hb][e][s] ----
// grid (64 mtiles, 24): tensor t = by>>3, n0 = (by&7)*128. Per-tensor operand order
// chosen so every store is a vectorized u16x4:
//   t<2 (Q,K): mfma(W,X) -> D[e][s]-frag: thread owns s=lane-col, 4 consec e regs
//   t=2 (V):   mfma(X,W) -> D[s][e]-frag: thread owns e=lane-col, 4 consec s regs
__global__ __launch_bounds__(256) void k_qkv(
    const u16* __restrict__ Xq, const u16* __restrict__ Xk, const u16* __restrict__ Xv,
    const u16* __restrict__ Wqt, const u16* __restrict__ Wkt, const u16* __restrict__ Wvt,
    u16* __restrict__ Qb, u16* __restrict__ Kb, u16* __restrict__ Vtb) {
  const int bx = blockIdx.x;
  const int by = blockIdx.y;
  const int t  = by >> 3;
  const int n0 = (by & 7) * 128;
  const u16* X  = t == 0 ? Xq  : t == 1 ? Xk  : Xv;
  const u16* Wt = t == 0 ? Wqt : t == 1 ? Wkt : Wvt;
  const int w = threadIdx.x >> 6, l = threadIdx.x & 63;
  const int lr = l & 15, lg = l >> 4;
  const int m0 = bx * 128 + w * 32;

  f32x4 acc[2][8] = {};
  const u16* Xp = X  + (size_t)(m0 + lr) * 1024 + lg * 8;
  const u16* Wp = Wt + (size_t)(n0 + lr) * 1024 + lg * 8;

  for (int k = 0; k < 1024; k += 32) {
    u16x8 xa[2];
    #pragma unroll
    for (int i = 0; i < 2; i++) xa[i] = *(const u16x8*)(Xp + (size_t)i * 16 * 1024 + k);
    #pragma unroll
    for (int j = 0; j < 8; j++) {
      u16x8 wb = *(const u16x8*)(Wp + (size_t)j * 16 * 1024 + k);
      if (t == 2) {
        #pragma unroll
        for (int i = 0; i < 2; i++) acc[i][j] = MFMA16(xa[i], wb, acc[i][j]);
      } else {
        #pragma unroll
        for (int i = 0; i < 2; i++) acc[i][j] = MFMA16(wb, xa[i], acc[i][j]);
      }
    }
  }

  const int bb = m0 >> 10, sbase = m0 & 1023;
  if (t == 2) {
    // D[row = s: i*16+lg*4+r][col = e: j*16+lr] -> V^T[e][s], 4 consecutive s
    #pragma unroll
    for (int i = 0; i < 2; i++)
      #pragma unroll
      for (int j = 0; j < 8; j++) {
        u16x4 v;
        #pragma unroll
        for (int r = 0; r < 4; r++) v[r] = f2bf(acc[i][j][r]);
        int eg = n0 + j * 16 + lr, h = eg >> 6, e = eg & 63;
        *(u16x4*)&Vtb[((size_t)(h * 8 + bb) * 64 + e) * 1024 + sbase + i * 16 + lg * 4] = v;
      }
  } else {
    u16* Out = t == 0 ? Qb : Kb;
    // D[row = e: j*16+lg*4+r][col = s: i*16+lr] -> Out[s][e], 4 consecutive e
    #pragma unroll
    for (int i = 0; i < 2; i++)
      #pragma unroll
      for (int j = 0; j < 8; j++) {
        u16x4 v;
        #pragma unroll
        for (int r = 0; r < 4; r++) v[r] = f2bf(acc[i][j][r]);
        int eg = n0 + j * 16 + lg * 4, h = eg >> 6, e = eg & 63;
        int s = sbase + i * 16 + lr;
        *(u16x4*)&Out[((size_t)(h * 8 + bb) * 1024 + s) * 64 + e] = v;
      }
  }
}

// ---- attention: wg = (hb, 16 q rows); swapped QK^T, per-wave full-K PV ----
// LDS exactly 32 KB -> 5 wg/CU. pbuf XOR-swizzled (byte ^= (row&7)<<4), reds aliased in.
__global__ __launch_bounds__(256, 5) void k_attn(const u16* __restrict__ Qb,
    const u16* __restrict__ Kb, const u16* __restrict__ Vtb,
    float* __restrict__ attn_out, u16* __restrict__ AO) {
  const int qt = blockIdx.x;        // 64
  const int hb = blockIdx.y;        // 128
  const int w  = threadIdx.x >> 6;
  const int l  = threadIdx.x & 63;
  const int lr = l & 15, lg = l >> 4;
  const int q0 = qt * 16;

  __shared__ __align__(16) u16 pbuf[16 * 1024];   // 32 KB, swizzled
  float* redm = (float*)pbuf;        // [4][16], dead before pbuf writes
  float* reds = (float*)pbuf + 64;   // [4][16]

  // --- QK^T swapped: mfma(K,Q) -> thread holds S[q=lr][k = w*256 + j*16 + lg*4 + r]
  const u16* Qp = Qb + ((size_t)hb * 1024 + q0 + lr) * 64 + lg * 8;
  const u16* Kp = Kb + ((size_t)hb * 1024 + w * 256 + lr) * 64 + lg * 8;
  u16x8 q_lo = *(const u16x8*)Qp;
  u16x8 q_hi = *(const u16x8*)(Qp + 32);

  f32x4 sacc[16] = {};
  #pragma unroll
  for (int j = 0; j < 16; j++) {
    u16x8 k0 = *(const u16x8*)(Kp + (size_t)j * 16 * 64);
    u16x8 k1 = *(const u16x8*)(Kp + (size_t)j * 16 * 64 + 32);
    sacc[j] = MFMA16(k0, q_lo, sacc[j]);
    sacc[j] = MFMA16(k1, q_hi, sacc[j]);
  }

  // --- row max (row = lr, local over j,r then lg groups then waves) ---
  float mx = sacc[0][0];
  #pragma unroll
  for (int j = 0; j < 16; j++)
    #pragma unroll
    for (int r = 0; r < 4; r++) mx = fmaxf(mx, sacc[j][r]);
  mx = fmaxf(mx, __shfl_xor(mx, 16));
  mx = fmaxf(mx, __shfl_xor(mx, 32));
  if (l < 16) redm[w * 16 + lr] = mx;
  __syncthreads();
  mx = fmaxf(fmaxf(redm[lr], redm[16 + lr]), fmaxf(redm[32 + lr], redm[48 + lr]));

  // --- exp + row sum ---
  float sum = 0.f;
  #pragma unroll
  for (int j = 0; j < 16; j++)
    #pragma unroll
    for (int r = 0; r < 4; r++) {
      float p = __expf(sacc[j][r] - mx);
      sacc[j][r] = p;
      sum += p;
    }
  sum += __shfl_xor(sum, 16);
  sum += __shfl_xor(sum, 32);
  if (l < 16) reds[w * 16 + lr] = sum;
  __syncthreads();
  const float inv = 1.0f / (reds[lr] + reds[16 + lr] + reds[32 + lr] + reds[48 + lr]);

  // --- normalize + vectorized f32 attn stores (float4 per j) ---
  #pragma unroll
  for (int j = 0; j < 16; j++) sacc[j] *= inv;
  float* Ap = attn_out + ((size_t)hb * 1024 + q0 + lr) * 1024 + w * 256 + lg * 4;
  #pragma unroll
  for (int j = 0; j < 16; j++) *(f32x4*)(Ap + j * 16) = sacc[j];

  __syncthreads();   // reds fully read before pbuf overwrites the aliased bytes

  // --- P -> swizzled pbuf (bf16) ---
  #pragma unroll
  for (int j = 0; j < 16; j++) {
    u16x4 pb;
    #pragma unroll
    for (int r = 0; r < 4; r++) pb[r] = f2bf(sacc[j][r]);
    int k0 = w * 256 + j * 16 + lg * 4;
    int byte = (lr * 2048 + k0 * 2) ^ ((lr & 7) << 4);
    *(u16x4*)((char*)pbuf + byte) = pb;
  }
  __syncthreads();

  // --- PV: wave w owns e-tile [w*16, w*16+16) over full K=1024 ---
  f32x4 oacc = {};
  const u16* Vp = Vtb + ((size_t)hb * 64 + w * 16 + lr) * 1024 + lg * 8;
  #pragma unroll
  for (int kk = 0; kk < 32; kk++) {
    int byte = (lr * 2048 + (kk * 32 + lg * 8) * 2) ^ ((lr & 7) << 4);
    u16x8 a = *(u16x8*)((char*)pbuf + byte);
    u16x8 b = *(const u16x8*)(Vp + kk * 32);
    oacc = MFMA16(a, b, oacc);
  }

  const int bb = hb & 7, hh = hb >> 3;
  #pragma unroll
  for (int r = 0; r < 4; r++)
    AO[((size_t)bb * 1024 + q0 + lg * 4 + r) * 1024 + hh * 64 + w * 16 + lr] = f2bf(oacc[r]);
}

// ---- projection + bias + residual + LayerNorm ----
__global__ __launch_bounds__(512) void k_proj_ln(const u16* __restrict__ AO,
    const u16* __restrict__ Wpt, const float* __restrict__ bp,
    const float* __restrict__ query, const float* __restrict__ gamma,
    const float* __restrict__ beta, float* __restrict__ y) {
  const int w  = threadIdx.x >> 6;
  const int l  = threadIdx.x & 63;
  const int lr = l & 15, lg = l >> 4;
  const int wm = w >> 2, wn = w & 3;
  const int m0 = blockIdx.x * 32 + wm * 16;
  const int n0 = wn * 256;

  __shared__ float reds1[4][2][16];
  __shared__ float reds2[4][2][16];

  f32x4 acc[16] = {};
  const u16* Ap = AO + (size_t)(m0 + lr) * 1024 + lg * 8;
  const u16* Bp = Wpt + (size_t)(n0 + lr) * 1024 + lg * 8;

  for (int k = 0; k < 1024; k += 32) {
    u16x8 a = *(const u16x8*)(Ap + k);
    #pragma unroll
    for (int j = 0; j < 16; j++) {
      u16x8 b = *(const u16x8*)(Bp + (size_t)j * 16 * 1024 + k);
      acc[j] = MFMA16(a, b, acc[j]);
    }
  }

  #pragma unroll
  for (int j = 0; j < 16; j++)
    #pragma unroll
    for (int r = 0; r < 4; r++) {
      int m = m0 + lg * 4 + r;
      int col = n0 + j * 16 + lr;
      acc[j][r] += bp[col] + query[(size_t)m * 1024 + col];
    }

  float s1[4], s2[4];
  #pragma unroll
  for (int r = 0; r < 4; r++) {
    float s = 0.f, q = 0.f;
    #pragma unroll
    for (int j = 0; j < 16; j++) { float v = acc[j][r]; s += v; q += v * v; }
    #pragma unroll
    for (int off = 1; off < 16; off <<= 1) { s += __shfl_xor(s, off); q += __shfl_xor(q, off); }
    s1[r] = s; s2[r] = q;
  }
  if (lr == 0) {
    #pragma unroll
    for (int r = 0; r < 4; r++) {
      reds1[wn][wm][lg * 4 + r] = s1[r];
      reds2[wn][wm][lg * 4 + r] = s2[r];
    }
  }
  __syncthreads();
  #pragma unroll
  for (int r = 0; r < 4; r++) {
    int row = lg * 4 + r;
    float S1 = reds1[0][wm][row] + reds1[1][wm][row] + reds1[2][wm][row] + reds1[3][wm][row];
    float S2 = reds2[0][wm][row] + reds2[1][wm][row] + reds2[2][wm][row] + reds2[3][wm][row];
    float mu = S1 * (1.0f / 1024.0f);
    float var = S2 * (1.0f / 1024.0f) - mu * mu;
    float rstd = rsqrtf(var + LN_EPS);
    int m = m0 + lg * 4 + r;
    #pragma unroll
    for (int j = 0; j < 16; j++) {
      int col = n0 + j * 16 + lr;
      y[(size_t)m * 1024 + col] = (acc[j][r] - mu) * rstd * gamma[col] + beta[col];
    }
  }
}

extern "C" void kernel_launch(void* const* d_in, const int* in_sizes, int n_in,
                              void* d_out, int out_size, void* d_ws, size_t ws_size,
                              hipStream_t stream) {
  const float* query  = (const float*)d_in[0];
  const float* keys   = (const float*)d_in[1];
  const float* values = (const float*)d_in[2];
  const float* Wq     = (const float*)d_in[3];
  const float* Wk     = (const float*)d_in[4];
  const float* Wv     = (const float*)d_in[5];
  const float* Wp     = (const float*)d_in[6];
  const float* bp     = (const float*)d_in[7];
  const float* gamma  = (const float*)d_in[8];
  const float* beta   = (const float*)d_in[9];

  float* y        = (float*)d_out;                         // [8,1024,1024]
  float* attn_out = (float*)d_out + (size_t)B_ * S_ * D_;  // [128,1024,1024]

  u16* ws  = (u16*)d_ws;
  u16* Wqt = ws;                   // 1M elems each
  u16* Wkt = Wqt + (1 << 20);
  u16* Wvt = Wkt + (1 << 20);
  u16* Wpt = Wvt + (1 << 20);
  u16* Xqb = Wpt + (1 << 20);      // 8M each
  u16* Xkb = Xqb + (8 << 20);
  u16* Xvb = Xkb + (8 << 20);
  u16* Qb  = Xvb + (8 << 20);
  u16* Kb  = Qb + (8 << 20);
  u16* Vtb = Kb + (8 << 20);
  u16* AO  = Vtb + (8 << 20);      // 8M

  k_transpose_w<<<4096, 256, 0, stream>>>(Wq, Wqt, 1.0f / 32.0f);  // fold 1/sqrt(1024)
  k_transpose_w<<<4096, 256, 0, stream>>>(Wk, Wkt, 1.0f);
  k_transpose_w<<<4096, 256, 0, stream>>>(Wv, Wvt, 1.0f);
  k_transpose_wp<<<4096, 256, 0, stream>>>(Wp, Wpt);
  k_convert<<<4096, 256, 0, stream>>>(query,  Xqb);
  k_convert<<<4096, 256, 0, stream>>>(keys,   Xkb);
  k_convert<<<4096, 256, 0, stream>>>(values, Xvb);

  k_qkv<<<dim3(64, 24), 256, 0, stream>>>(Xqb, Xkb, Xvb, Wqt, Wkt, Wvt, Qb, Kb, Vtb);

  k_attn<<<dim3(64, 128), 256, 0, stream>>>(Qb, Kb, Vtb, attn_out, AO);

  k_proj_ln<<<256, 512, 0, stream>>>(AO, Wpt, bp, query, gamma, beta, y);
}

// Round 3
// 551.480 us; speedup vs baseline: 1.8592x; 1.8592x over previous
//
#include <hip/hip_runtime.h>
#include <hip/hip_bf16.h>

#define H_ 16
#define B_ 8
#define S_ 1024
#define D_ 1024
#define E_ 64
#define HB_ 128
#define LN_EPS 1e-5f

typedef unsigned short u16;
typedef __bf16 bf16x8 __attribute__((ext_vector_type(8)));
typedef u16 u16x8 __attribute__((ext_vector_type(8)));
typedef u16 u16x4 __attribute__((ext_vector_type(4)));
typedef float f32x4 __attribute__((ext_vector_type(4)));

#define MFMA16(a, b, c) __builtin_amdgcn_mfma_f32_16x16x32_bf16( \
    __builtin_bit_cast(bf16x8, (a)), __builtin_bit_cast(bf16x8, (b)), (c), 0, 0, 0)

// async global->LDS, 16B per lane; LDS dest must be wave-uniform base (+lane*16 by HW)
#define GLL16(gp, lp) __builtin_amdgcn_global_load_lds( \
    (const __attribute__((address_space(1))) void*)(gp), \
    (__attribute__((address_space(3))) void*)(lp), 16, 0, 0)

__device__ __forceinline__ u16 f2bf(float x) {
  union { float f; unsigned u; } v; v.f = x;
  unsigned r = v.u + 0x7fffu + ((v.u >> 16) & 1u);
  return (u16)(r >> 16);
}

// ---- prep: W [H][D][E] f32 -> Wt [(h*64+e)][D] bf16 (scaled) ----
__global__ void k_transpose_w(const float* __restrict__ W, u16* __restrict__ Wt, float scale) {
  int tid = blockIdx.x * 256 + threadIdx.x;   // H*D*E = 1,048,576
  int e = tid & 63, d = (tid >> 6) & 1023, h = tid >> 16;
  Wt[(size_t)(h * 64 + e) * 1024 + d] = f2bf(W[tid] * scale);
}

// ---- prep: Wp [K][N] f32 -> Wpt [N][K] bf16 ----
__global__ void k_transpose_wp(const float* __restrict__ W, u16* __restrict__ Wt) {
  int tid = blockIdx.x * 256 + threadIdx.x;   // 1,048,576
  int n = tid & 1023, k = tid >> 10;
  Wt[(size_t)n * 1024 + k] = f2bf(W[tid]);
}

// ---- prep: X f32 -> bf16, 8 elems/thread ----
__global__ void k_convert(const float* __restrict__ X, u16* __restrict__ Y) {
  int i = (blockIdx.x * 256 + threadIdx.x) * 8;
  float4 a = *(const float4*)(X + i);
  float4 b = *(const float4*)(X + i + 4);
  u16x8 v;
  v[0] = f2bf(a.x); v[1] = f2bf(a.y); v[2] = f2bf(a.z); v[3] = f2bf(a.w);
  v[4] = f2bf(b.x); v[5] = f2bf(b.y); v[6] = f2bf(b.z); v[7] = f2bf(b.w);
  *(u16x8*)(Y + i) = v;
}

// ---- m97-structure GEMM: 128x128 tile, BK=32, 4 waves, global_load_lds staging ----
// MODE 0: C=X@W' for Q,K (swapped mfma -> u16x4 e-major stores into Qb/Kb [hb][s][64])
// MODE 1: C=X@W' for V  (normal mfma -> u16x4 s-major stores into Vtb [hb][e][s])
// MODE 2: C=AO@Wp' proj (swapped mfma -> f32x4 stores of C+bias+residual into P [m][1024])
template<int MODE>
__global__ __launch_bounds__(256) void k_gemm(
    const u16* __restrict__ X0, const u16* __restrict__ X1,
    const u16* __restrict__ Ball,
    u16* __restrict__ O0, u16* __restrict__ O1,
    float* __restrict__ Pf, const float* __restrict__ bp,
    const float* __restrict__ query) {
  const int bx = blockIdx.x, by = blockIdx.y;
  const int l  = threadIdx.x & 63;
  const int w  = threadIdx.x >> 6;
  const int lr = l & 15, lg = l >> 4;
  const int wr = w >> 1, wc = w & 1;
  const int m0 = bx * 128, n0 = by * 128;

  const u16* A = (MODE == 0 && by >= 8) ? X1 : X0;

  __shared__ __align__(16) u16 As[128 * 32];
  __shared__ __align__(16) u16 Bs[128 * 32];

  // staging: instr i covers LDS bytes [i*4096 + w*1024, +1024): row = i*64+w*16+(l>>2), kbyte=(l&3)*16
  const int srow = w * 16 + (l >> 2);
  const int scol = (l & 3) * 8;
  const u16* Ag = A    + (size_t)(m0 + srow) * 1024 + scol;
  const u16* Bg = Ball + (size_t)(n0 + srow) * 1024 + scol;
  u16* AsB0 = As + w * 512;           // uniform per wave
  u16* BsB0 = Bs + w * 512;

  f32x4 acc[4][4] = {};

  for (int kt = 0; kt < 1024; kt += 32) {
    GLL16(Ag + kt,             AsB0);
    GLL16(Ag + 64 * 1024 + kt, AsB0 + 2048);
    GLL16(Bg + kt,             BsB0);
    GLL16(Bg + 64 * 1024 + kt, BsB0 + 2048);
    __syncthreads();   // compiler drains vmcnt(0) here -> staged data visible

    u16x8 af[4], bf[4];
    #pragma unroll
    for (int mi = 0; mi < 4; mi++)
      af[mi] = *(const u16x8*)&As[(wr * 64 + mi * 16 + lr) * 32 + lg * 8];
    #pragma unroll
    for (int ni = 0; ni < 4; ni++)
      bf[ni] = *(const u16x8*)&Bs[(wc * 64 + ni * 16 + lr) * 32 + lg * 8];

    #pragma unroll
    for (int mi = 0; mi < 4; mi++)
      #pragma unroll
      for (int ni = 0; ni < 4; ni++) {
        if (MODE == 1) acc[mi][ni] = MFMA16(af[mi], bf[ni], acc[mi][ni]);
        else           acc[mi][ni] = MFMA16(bf[ni], af[mi], acc[mi][ni]);
      }
    __syncthreads();   // LDS consumed before next stage overwrites
  }

  if (MODE == 0) {
    // D[row=n][col=m]: thread owns 4 consecutive e at one s
    u16* Out = (by >= 8) ? O1 : O0;
    const int h = (by & 7) * 2 + wc;
    #pragma unroll
    for (int mi = 0; mi < 4; mi++) {
      int s = m0 + wr * 64 + mi * 16 + lr;
      int bb = s >> 10, ss = s & 1023;
      #pragma unroll
      for (int ni = 0; ni < 4; ni++) {
        u16x4 v;
        #pragma unroll
        for (int r = 0; r < 4; r++) v[r] = f2bf(acc[mi][ni][r]);
        *(u16x4*)&Out[((size_t)(h * 8 + bb) * 1024 + ss) * 64 + ni * 16 + lg * 4] = v;
      }
    }
  } else if (MODE == 1) {
    // D[row=m][col=n]: thread owns 4 consecutive s at one e
    const int h = by * 2 + wc;
    #pragma unroll
    for (int mi = 0; mi < 4; mi++) {
      int s = m0 + wr * 64 + mi * 16 + lg * 4;
      int bb = s >> 10, ss = s & 1023;
      #pragma unroll
      for (int ni = 0; ni < 4; ni++) {
        u16x4 v;
        #pragma unroll
        for (int r = 0; r < 4; r++) v[r] = f2bf(acc[mi][ni][r]);
        *(u16x4*)&O0[((size_t)(h * 8 + bb) * 64 + ni * 16 + lr) * 1024 + ss] = v;
      }
    }
  } else {
    // D[row=n][col=m]: thread owns 4 consecutive n at one m; fuse +bias+residual
    #pragma unroll
    for (int mi = 0; mi < 4; mi++) {
      int m = m0 + wr * 64 + mi * 16 + lr;
      #pragma unroll
      for (int ni = 0; ni < 4; ni++) {
        int n = n0 + wc * 64 + ni * 16 + lg * 4;
        f32x4 b4 = *(const f32x4*)(bp + n);
        f32x4 q4 = *(const f32x4*)(query + (size_t)m * 1024 + n);
        f32x4 o = acc[mi][ni] + b4 + q4;
        *(f32x4*)(Pf + (size_t)m * 1024 + n) = o;
      }
    }
  }
}

// ---- attention: wg = (hb, 16 q rows); swapped QK^T, per-wave full-K PV ----
__global__ __launch_bounds__(256, 5) void k_attn(const u16* __restrict__ Qb,
    const u16* __restrict__ Kb, const u16* __restrict__ Vtb,
    float* __restrict__ attn_out, u16* __restrict__ AO) {
  const int qt = blockIdx.x;        // 64
  const int hb = blockIdx.y;        // 128
  const int w  = threadIdx.x >> 6;
  const int l  = threadIdx.x & 63;
  const int lr = l & 15, lg = l >> 4;
  const int q0 = qt * 16;

  __shared__ __align__(16) u16 pbuf[16 * 1024];   // 32 KB, swizzled
  float* redm = (float*)pbuf;        // [4][16], dead before pbuf writes
  float* reds = (float*)pbuf + 64;   // [4][16]

  const u16* Qp = Qb + ((size_t)hb * 1024 + q0 + lr) * 64 + lg * 8;
  const u16* Kp = Kb + ((size_t)hb * 1024 + w * 256 + lr) * 64 + lg * 8;
  u16x8 q_lo = *(const u16x8*)Qp;
  u16x8 q_hi = *(const u16x8*)(Qp + 32);

  f32x4 sacc[16] = {};
  #pragma unroll
  for (int j = 0; j < 16; j++) {
    u16x8 k0 = *(const u16x8*)(Kp + (size_t)j * 16 * 64);
    u16x8 k1 = *(const u16x8*)(Kp + (size_t)j * 16 * 64 + 32);
    sacc[j] = MFMA16(k0, q_lo, sacc[j]);
    sacc[j] = MFMA16(k1, q_hi, sacc[j]);
  }

  float mx = sacc[0][0];
  #pragma unroll
  for (int j = 0; j < 16; j++)
    #pragma unroll
    for (int r = 0; r < 4; r++) mx = fmaxf(mx, sacc[j][r]);
  mx = fmaxf(mx, __shfl_xor(mx, 16));
  mx = fmaxf(mx, __shfl_xor(mx, 32));
  if (l < 16) redm[w * 16 + lr] = mx;
  __syncthreads();
  mx = fmaxf(fmaxf(redm[lr], redm[16 + lr]), fmaxf(redm[32 + lr], redm[48 + lr]));

  float sum = 0.f;
  #pragma unroll
  for (int j = 0; j < 16; j++)
    #pragma unroll
    for (int r = 0; r < 4; r++) {
      float p = __expf(sacc[j][r] - mx);
      sacc[j][r] = p;
      sum += p;
    }
  sum += __shfl_xor(sum, 16);
  sum += __shfl_xor(sum, 32);
  if (l < 16) reds[w * 16 + lr] = sum;
  __syncthreads();
  const float inv = 1.0f / (reds[lr] + reds[16 + lr] + reds[32 + lr] + reds[48 + lr]);

  #pragma unroll
  for (int j = 0; j < 16; j++) sacc[j] *= inv;
  float* Ap = attn_out + ((size_t)hb * 1024 + q0 + lr) * 1024 + w * 256 + lg * 4;
  #pragma unroll
  for (int j = 0; j < 16; j++) *(f32x4*)(Ap + j * 16) = sacc[j];

  __syncthreads();   // reds fully read before pbuf overwrites the aliased bytes

  #pragma unroll
  for (int j = 0; j < 16; j++) {
    u16x4 pb;
    #pragma unroll
    for (int r = 0; r < 4; r++) pb[r] = f2bf(sacc[j][r]);
    int k0 = w * 256 + j * 16 + lg * 4;
    int byte = (lr * 2048 + k0 * 2) ^ ((lr & 7) << 4);
    *(u16x4*)((char*)pbuf + byte) = pb;
  }
  __syncthreads();

  f32x4 oacc = {};
  const u16* Vp = Vtb + ((size_t)hb * 64 + w * 16 + lr) * 1024 + lg * 8;
  #pragma unroll
  for (int kk = 0; kk < 32; kk++) {
    int byte = (lr * 2048 + (kk * 32 + lg * 8) * 2) ^ ((lr & 7) << 4);
    u16x8 a = *(u16x8*)((char*)pbuf + byte);
    u16x8 b = *(const u16x8*)(Vp + kk * 32);
    oacc = MFMA16(a, b, oacc);
  }

  const int bb = hb & 7, hh = hb >> 3;
  #pragma unroll
  for (int r = 0; r < 4; r++)
    AO[((size_t)bb * 1024 + q0 + lg * 4 + r) * 1024 + hh * 64 + w * 16 + lr] = f2bf(oacc[r]);
}

// ---- standalone LayerNorm over P rows (bias+residual already in P) ----
__global__ __launch_bounds__(256) void k_ln(const float* __restrict__ P,
    const float* __restrict__ gamma, const float* __restrict__ beta,
    float* __restrict__ y) {
  const int row = blockIdx.x * 4 + (threadIdx.x >> 6);
  const int l = threadIdx.x & 63;
  const float* p = P + (size_t)row * 1024 + l * 4;
  f32x4 v[4];
  float s = 0.f, s2 = 0.f;
  #pragma unroll
  for (int i = 0; i < 4; i++) {
    v[i] = *(const f32x4*)(p + i * 256);
    #pragma unroll
    for (int r = 0; r < 4; r++) { s += v[i][r]; s2 += v[i][r] * v[i][r]; }
  }
  #pragma unroll
  for (int off = 1; off < 64; off <<= 1) {
    s += __shfl_xor(s, off);
    s2 += __shfl_xor(s2, off);
  }
  float mu = s * (1.0f / 1024.0f);
  float var = s2 * (1.0f / 1024.0f) - mu * mu;
  float rstd = rsqrtf(var + LN_EPS);
  float* yp = y + (size_t)row * 1024 + l * 4;
  #pragma unroll
  for (int i = 0; i < 4; i++) {
    f32x4 g = *(const f32x4*)(gamma + l * 4 + i * 256);
    f32x4 b = *(const f32x4*)(beta + l * 4 + i * 256);
    f32x4 o;
    #pragma unroll
    for (int r = 0; r < 4; r++) o[r] = (v[i][r] - mu) * rstd * g[r] + b[r];
    *(f32x4*)(yp + i * 256) = o;
  }
}

extern "C" void kernel_launch(void* const* d_in, const int* in_sizes, int n_in,
                              void* d_out, int out_size, void* d_ws, size_t ws_size,
                              hipStream_t stream) {
  const float* query  = (const float*)d_in[0];
  const float* keys   = (const float*)d_in[1];
  const float* values = (const float*)d_in[2];
  const float* Wq     = (const float*)d_in[3];
  const float* Wk     = (const float*)d_in[4];
  const float* Wv     = (const float*)d_in[5];
  const float* Wp     = (const float*)d_in[6];
  const float* bp     = (const float*)d_in[7];
  const float* gamma  = (const float*)d_in[8];
  const float* beta   = (const float*)d_in[9];

  float* y        = (float*)d_out;                         // [8,1024,1024]
  float* attn_out = (float*)d_out + (size_t)B_ * S_ * D_;  // [128,1024,1024]

  u16* ws  = (u16*)d_ws;
  u16* Wqt = ws;                   // 1M elems each; Wqt+Wkt contiguous = fused QK B-matrix
  u16* Wkt = Wqt + (1 << 20);
  u16* Wvt = Wkt + (1 << 20);
  u16* Wpt = Wvt + (1 << 20);
  u16* Xqb = Wpt + (1 << 20);      // 8M each
  u16* Xkb = Xqb + (8 << 20);
  u16* Xvb = Xkb + (8 << 20);
  u16* Qb  = Xvb + (8 << 20);
  u16* Kb  = Qb + (8 << 20);
  u16* Vtb = Kb + (8 << 20);
  u16* AO  = Vtb + (8 << 20);      // 8M
  float* P = (float*)Xqb;          // 8M f32 = 32MB, overlays Xqb+Xkb (dead after QKV GEMM)

  k_transpose_w<<<4096, 256, 0, stream>>>(Wq, Wqt, 1.0f / 32.0f);  // fold 1/sqrt(1024)
  k_transpose_w<<<4096, 256, 0, stream>>>(Wk, Wkt, 1.0f);
  k_transpose_w<<<4096, 256, 0, stream>>>(Wv, Wvt, 1.0f);
  k_transpose_wp<<<4096, 256, 0, stream>>>(Wp, Wpt);
  k_convert<<<4096, 256, 0, stream>>>(query,  Xqb);
  k_convert<<<4096, 256, 0, stream>>>(keys,   Xkb);
  k_convert<<<4096, 256, 0, stream>>>(values, Xvb);

  k_gemm<0><<<dim3(64, 16), 256, 0, stream>>>(Xqb, Xkb, Wqt, Qb, Kb, nullptr, nullptr, nullptr);
  k_gemm<1><<<dim3(64, 8),  256, 0, stream>>>(Xvb, nullptr, Wvt, Vtb, nullptr, nullptr, nullptr, nullptr);

  k_attn<<<dim3(64, 128), 256, 0, stream>>>(Qb, Kb, Vtb, attn_out, AO);

  k_gemm<2><<<dim3(64, 8),  256, 0, stream>>>(AO, nullptr, Wpt, nullptr, nullptr, P, bp, query);
  k_ln<<<2048, 256, 0, stream>>>(P, gamma, beta, y);
}

// Round 4
// 438.877 us; speedup vs baseline: 2.3363x; 1.2566x over previous
//
#include <hip/hip_runtime.h>
#include <hip/hip_bf16.h>

#define H_ 16
#define B_ 8
#define S_ 1024
#define D_ 1024
#define E_ 64
#define HB_ 128
#define LN_EPS 1e-5f

typedef unsigned short u16;
typedef __bf16 bf16x8 __attribute__((ext_vector_type(8)));
typedef u16 u16x8 __attribute__((ext_vector_type(8)));
typedef u16 u16x4 __attribute__((ext_vector_type(4)));
typedef float f32x4 __attribute__((ext_vector_type(4)));

#define MFMA16(a, b, c) __builtin_amdgcn_mfma_f32_16x16x32_bf16( \
    __builtin_bit_cast(bf16x8, (a)), __builtin_bit_cast(bf16x8, (b)), (c), 0, 0, 0)

// async global->LDS, 16B per lane; LDS dest must be wave-uniform base (+lane*16 by HW)
#define GLL16(gp, lp) __builtin_amdgcn_global_load_lds( \
    (const __attribute__((address_space(1))) void*)(gp), \
    (__attribute__((address_space(3))) void*)(lp), 16, 0, 0)

__device__ __forceinline__ u16 f2bf(float x) {
  union { float f; unsigned u; } v; v.f = x;
  unsigned r = v.u + 0x7fffu + ((v.u >> 16) & 1u);
  return (u16)(r >> 16);
}

// ---- tiled transpose: in R x C f32 (slice z) -> out C x R bf16, scaled ----
__global__ __launch_bounds__(256) void k_transpose_tile(const float* __restrict__ in,
    u16* __restrict__ out, int R, int C, float scale) {
  __shared__ float tile[64][65];
  const int rt = blockIdx.x * 64, ct = blockIdx.y * 64;
  const size_t so = (size_t)blockIdx.z * R * C;
  const float* I = in + so;
  u16* O = out + so;
  const int t = threadIdx.x;
  const int c4 = (t & 15) * 4;
  #pragma unroll
  for (int i = 0; i < 4; i++) {
    int r = i * 16 + (t >> 4);
    f32x4 v = *(const f32x4*)&I[(size_t)(rt + r) * C + ct + c4];
    tile[r][c4 + 0] = v[0]; tile[r][c4 + 1] = v[1];
    tile[r][c4 + 2] = v[2]; tile[r][c4 + 3] = v[3];
  }
  __syncthreads();
  #pragma unroll
  for (int i = 0; i < 4; i++) {
    int oc = i * 16 + (t >> 4);
    u16x4 v;
    #pragma unroll
    for (int r = 0; r < 4; r++) v[r] = f2bf(tile[c4 + r][oc] * scale);
    *(u16x4*)&O[(size_t)(ct + oc) * R + rt + c4] = v;
  }
}

// ---- prep: X f32 -> bf16, 8 elems/thread ----
__global__ void k_convert(const float* __restrict__ X, u16* __restrict__ Y) {
  int i = (blockIdx.x * 256 + threadIdx.x) * 8;
  float4 a = *(const float4*)(X + i);
  float4 b = *(const float4*)(X + i + 4);
  u16x8 v;
  v[0] = f2bf(a.x); v[1] = f2bf(a.y); v[2] = f2bf(a.z); v[3] = f2bf(a.w);
  v[4] = f2bf(b.x); v[5] = f2bf(b.y); v[6] = f2bf(b.z); v[7] = f2bf(b.w);
  *(u16x8*)(Y + i) = v;
}

// ---- m97-structure GEMM: 128x128 tile, BK=32, 4 waves, global_load_lds staging ----
// MODE 0: C=X@W' for Q,K (swapped mfma -> u16x4 e-major stores into Qb/Kb [hb][s][64])
// MODE 1: C=X@W' for V  (normal mfma -> u16x4 s-major stores into Vtb [hb][e][s])
// MODE 2: C=AO@Wp' proj (swapped mfma -> f32x4 stores of C+bias+residual into P [m][1024])
template<int MODE>
__global__ __launch_bounds__(256) void k_gemm(
    const u16* __restrict__ X0, const u16* __restrict__ X1,
    const u16* __restrict__ Ball,
    u16* __restrict__ O0, u16* __restrict__ O1,
    float* __restrict__ Pf, const float* __restrict__ bp,
    const float* __restrict__ query) {
  const int bx = blockIdx.x, by = blockIdx.y;
  const int l  = threadIdx.x & 63;
  const int w  = threadIdx.x >> 6;
  const int lr = l & 15, lg = l >> 4;
  const int wr = w >> 1, wc = w & 1;
  const int m0 = bx * 128, n0 = by * 128;

  const u16* A = (MODE == 0 && by >= 8) ? X1 : X0;

  __shared__ __align__(16) u16 As[128 * 32];
  __shared__ __align__(16) u16 Bs[128 * 32];

  const int srow = w * 16 + (l >> 2);
  const int scol = (l & 3) * 8;
  const u16* Ag = A    + (size_t)(m0 + srow) * 1024 + scol;
  const u16* Bg = Ball + (size_t)(n0 + srow) * 1024 + scol;
  u16* AsB0 = As + w * 512;           // uniform per wave
  u16* BsB0 = Bs + w * 512;

  f32x4 acc[4][4] = {};

  for (int kt = 0; kt < 1024; kt += 32) {
    GLL16(Ag + kt,             AsB0);
    GLL16(Ag + 64 * 1024 + kt, AsB0 + 2048);
    GLL16(Bg + kt,             BsB0);
    GLL16(Bg + 64 * 1024 + kt, BsB0 + 2048);
    __syncthreads();

    u16x8 af[4], bf[4];
    #pragma unroll
    for (int mi = 0; mi < 4; mi++)
      af[mi] = *(const u16x8*)&As[(wr * 64 + mi * 16 + lr) * 32 + lg * 8];
    #pragma unroll
    for (int ni = 0; ni < 4; ni++)
      bf[ni] = *(const u16x8*)&Bs[(wc * 64 + ni * 16 + lr) * 32 + lg * 8];

    #pragma unroll
    for (int mi = 0; mi < 4; mi++)
      #pragma unroll
      for (int ni = 0; ni < 4; ni++) {
        if (MODE == 1) acc[mi][ni] = MFMA16(af[mi], bf[ni], acc[mi][ni]);
        else           acc[mi][ni] = MFMA16(bf[ni], af[mi], acc[mi][ni]);
      }
    __syncthreads();
  }

  if (MODE == 0) {
    u16* Out = (by >= 8) ? O1 : O0;
    const int h = (by & 7) * 2 + wc;
    #pragma unroll
    for (int mi = 0; mi < 4; mi++) {
      int s = m0 + wr * 64 + mi * 16 + lr;
      int bb = s >> 10, ss = s & 1023;
      #pragma unroll
      for (int ni = 0; ni < 4; ni++) {
        u16x4 v;
        #pragma unroll
        for (int r = 0; r < 4; r++) v[r] = f2bf(acc[mi][ni][r]);
        *(u16x4*)&Out[((size_t)(h * 8 + bb) * 1024 + ss) * 64 + ni * 16 + lg * 4] = v;
      }
    }
  } else if (MODE == 1) {
    const int h = by * 2 + wc;
    #pragma unroll
    for (int mi = 0; mi < 4; mi++) {
      int s = m0 + wr * 64 + mi * 16 + lg * 4;
      int bb = s >> 10, ss = s & 1023;
      #pragma unroll
      for (int ni = 0; ni < 4; ni++) {
        u16x4 v;
        #pragma unroll
        for (int r = 0; r < 4; r++) v[r] = f2bf(acc[mi][ni][r]);
        *(u16x4*)&O0[((size_t)(h * 8 + bb) * 64 + ni * 16 + lr) * 1024 + ss] = v;
      }
    }
  } else {
    #pragma unroll
    for (int mi = 0; mi < 4; mi++) {
      int m = m0 + wr * 64 + mi * 16 + lr;
      #pragma unroll
      for (int ni = 0; ni < 4; ni++) {
        int n = n0 + wc * 64 + ni * 16 + lg * 4;
        f32x4 b4 = *(const f32x4*)(bp + n);
        f32x4 q4 = *(const f32x4*)(query + (size_t)m * 1024 + n);
        f32x4 o = acc[mi][ni] + b4 + q4;
        *(f32x4*)(Pf + (size_t)m * 1024 + n) = o;
      }
    }
  }
}

// ---- attention: wg = (hb, 16 q rows); ONE barrier; all global stores after it ----
__global__ __launch_bounds__(256, 4) void k_attn(const u16* __restrict__ Qb,
    const u16* __restrict__ Kb, const u16* __restrict__ Vtb,
    float* __restrict__ attn_out, u16* __restrict__ AO) {
  const int qt = blockIdx.x;        // 64
  const int hb = blockIdx.y;        // 128
  const int w  = threadIdx.x >> 6;
  const int l  = threadIdx.x & 63;
  const int lr = l & 15, lg = l >> 4;
  const int q0 = qt * 16;

  __shared__ __align__(16) u16 pbuf[16 * 1024];   // 32 KB, swizzled; raw exp(s - wmax_w)
  __shared__ float wmaxs[4][16];
  __shared__ float wsums[4][16];

  // --- QK^T swapped: mfma(K,Q) -> thread holds S[q=lr][k = w*256 + j*16 + lg*4 + r]
  const u16* Qp = Qb + ((size_t)hb * 1024 + q0 + lr) * 64 + lg * 8;
  const u16* Kp = Kb + ((size_t)hb * 1024 + w * 256 + lr) * 64 + lg * 8;
  u16x8 q_lo = *(const u16x8*)Qp;
  u16x8 q_hi = *(const u16x8*)(Qp + 32);

  f32x4 sacc[16] = {};
  #pragma unroll
  for (int j = 0; j < 16; j++) {
    u16x8 k0 = *(const u16x8*)(Kp + (size_t)j * 16 * 64);
    u16x8 k1 = *(const u16x8*)(Kp + (size_t)j * 16 * 64 + 32);
    sacc[j] = MFMA16(k0, q_lo, sacc[j]);
    sacc[j] = MFMA16(k1, q_hi, sacc[j]);
  }

  // --- wave-local row max over this wave's 256-col slice ---
  float mx = sacc[0][0];
  #pragma unroll
  for (int j = 0; j < 16; j++)
    #pragma unroll
    for (int r = 0; r < 4; r++) mx = fmaxf(mx, sacc[j][r]);
  mx = fmaxf(mx, __shfl_xor(mx, 16));
  mx = fmaxf(mx, __shfl_xor(mx, 32));

  // --- exp(s - wmax) + wave-local sum ---
  float sum = 0.f;
  #pragma unroll
  for (int j = 0; j < 16; j++)
    #pragma unroll
    for (int r = 0; r < 4; r++) {
      float p = __expf(sacc[j][r] - mx);
      sacc[j][r] = p;
      sum += p;
    }
  sum += __shfl_xor(sum, 16);
  sum += __shfl_xor(sum, 32);

  // --- raw-exp P -> swizzled pbuf (bf16), before the barrier ---
  #pragma unroll
  for (int j = 0; j < 16; j++) {
    u16x4 pb;
    #pragma unroll
    for (int r = 0; r < 4; r++) pb[r] = f2bf(sacc[j][r]);
    int k0 = w * 256 + j * 16 + lg * 4;
    int byte = (lr * 2048 + k0 * 2) ^ ((lr & 7) << 4);
    *(u16x4*)((char*)pbuf + byte) = pb;
  }
  if (l < 16) { wmaxs[w][lr] = mx; wsums[w][lr] = sum; }

  __syncthreads();   // the only barrier: drains LDS writes only (no global stores yet)

  // --- combine: gmax, gsum, per-slice coefficients (all for row q = lr) ---
  float m0v = wmaxs[0][lr], m1v = wmaxs[1][lr], m2v = wmaxs[2][lr], m3v = wmaxs[3][lr];
  float gmax = fmaxf(fmaxf(m0v, m1v), fmaxf(m2v, m3v));
  float e0 = __expf(m0v - gmax), e1 = __expf(m1v - gmax);
  float e2 = __expf(m2v - gmax), e3 = __expf(m3v - gmax);
  float gsum = wsums[0][lr] * e0 + wsums[1][lr] * e1 + wsums[2][lr] * e2 + wsums[3][lr] * e3;
  float inv = 1.0f / gsum;
  float c0 = e0 * inv, c1 = e1 * inv, c2 = e2 * inv, c3 = e3 * inv;
  float scale_own = __expf(mx - gmax) * inv;   // == c_w for own wave

  // --- normalized attn f32 out (nontemporal; overlaps PV below) ---
  float* Ap = attn_out + ((size_t)hb * 1024 + q0 + lr) * 1024 + w * 256 + lg * 4;
  #pragma unroll
  for (int j = 0; j < 16; j++) {
    f32x4 v = sacc[j] * scale_own;
    __builtin_nontemporal_store(v, (f32x4*)(Ap + j * 16));
  }

  // --- PV with swapped operands: mfma(V, P) -> D[row=e][col=q=lr]
  //     per-k-slice partials, combined with per-slice coefs afterwards ---
  const u16* Vp = Vtb + ((size_t)hb * 64 + w * 16 + lr) * 1024 + lg * 8;
  f32x4 o0 = {}, o1 = {}, o2 = {}, o3 = {};
  #pragma unroll
  for (int i = 0; i < 4; i++)
    #pragma unroll
    for (int kk = 0; kk < 8; kk++) {
      int kb = i * 256 + kk * 32 + lg * 8;
      int byte = (lr * 2048 + kb * 2) ^ ((lr & 7) << 4);
      u16x8 p = *(u16x8*)((char*)pbuf + byte);
      u16x8 v = *(const u16x8*)(Vp + i * 256 + kk * 32);
      if (i == 0) o0 = MFMA16(v, p, o0);
      else if (i == 1) o1 = MFMA16(v, p, o1);
      else if (i == 2) o2 = MFMA16(v, p, o2);
      else o3 = MFMA16(v, p, o3);
    }

  // --- combine + AO store: q = lr, e = w*16 + lg*4 + r -> one u16x4 ---
  const int bb = hb & 7, hh = hb >> 3;
  u16x4 ov;
  #pragma unroll
  for (int r = 0; r < 4; r++)
    ov[r] = f2bf(o0[r] * c0 + o1[r] * c1 + o2[r] * c2 + o3[r] * c3);
  *(u16x4*)&AO[((size_t)bb * 1024 + q0 + lr) * 1024 + hh * 64 + w * 16 + lg * 4] = ov;
}

// ---- standalone LayerNorm over P rows (bias+residual already in P) ----
__global__ __launch_bounds__(256) void k_ln(const float* __restrict__ P,
    const float* __restrict__ gamma, const float* __restrict__ beta,
    float* __restrict__ y) {
  const int row = blockIdx.x * 4 + (threadIdx.x >> 6);
  const int l = threadIdx.x & 63;
  const float* p = P + (size_t)row * 1024 + l * 4;
  f32x4 v[4];
  float s = 0.f, s2 = 0.f;
  #pragma unroll
  for (int i = 0; i < 4; i++) {
    v[i] = *(const f32x4*)(p + i * 256);
    #pragma unroll
    for (int r = 0; r < 4; r++) { s += v[i][r]; s2 += v[i][r] * v[i][r]; }
  }
  #pragma unroll
  for (int off = 1; off < 64; off <<= 1) {
    s += __shfl_xor(s, off);
    s2 += __shfl_xor(s2, off);
  }
  float mu = s * (1.0f / 1024.0f);
  float var = s2 * (1.0f / 1024.0f) - mu * mu;
  float rstd = rsqrtf(var + LN_EPS);
  float* yp = y + (size_t)row * 1024 + l * 4;
  #pragma unroll
  for (int i = 0; i < 4; i++) {
    f32x4 g = *(const f32x4*)(gamma + l * 4 + i * 256);
    f32x4 b = *(const f32x4*)(beta + l * 4 + i * 256);
    f32x4 o;
    #pragma unroll
    for (int r = 0; r < 4; r++) o[r] = (v[i][r] - mu) * rstd * g[r] + b[r];
    __builtin_nontemporal_store(o, (f32x4*)(yp + i * 256));
  }
}

extern "C" void kernel_launch(void* const* d_in, const int* in_sizes, int n_in,
                              void* d_out, int out_size, void* d_ws, size_t ws_size,
                              hipStream_t stream) {
  const float* query  = (const float*)d_in[0];
  const float* keys   = (const float*)d_in[1];
  const float* values = (const float*)d_in[2];
  const float* Wq     = (const float*)d_in[3];
  const float* Wk     = (const float*)d_in[4];
  const float* Wv     = (const float*)d_in[5];
  const float* Wp     = (const float*)d_in[6];
  const float* bp     = (const float*)d_in[7];
  const float* gamma  = (const float*)d_in[8];
  const float* beta   = (const float*)d_in[9];

  float* y        = (float*)d_out;                         // [8,1024,1024]
  float* attn_out = (float*)d_out + (size_t)B_ * S_ * D_;  // [128,1024,1024]

  u16* ws  = (u16*)d_ws;
  u16* Wqt = ws;                   // 1M elems each; Wqt+Wkt contiguous = fused QK B-matrix
  u16* Wkt = Wqt + (1 << 20);
  u16* Wvt = Wkt + (1 << 20);
  u16* Wpt = Wvt + (1 << 20);
  u16* Xqb = Wpt + (1 << 20);      // 8M each
  u16* Xkb = Xqb + (8 << 20);
  u16* Xvb = Xkb + (8 << 20);
  u16* Qb  = Xvb + (8 << 20);
  u16* Kb  = Qb + (8 << 20);
  u16* Vtb = Kb + (8 << 20);
  u16* AO  = Vtb + (8 << 20);      // 8M
  float* P = (float*)Xqb;          // 8M f32 = 32MB, overlays Xqb+Xkb (dead after QKV GEMM)

  k_transpose_tile<<<dim3(16, 1, 16), 256, 0, stream>>>(Wq, Wqt, 1024, 64, 1.0f / 32.0f);
  k_transpose_tile<<<dim3(16, 1, 16), 256, 0, stream>>>(Wk, Wkt, 1024, 64, 1.0f);
  k_transpose_tile<<<dim3(16, 1, 16), 256, 0, stream>>>(Wv, Wvt, 1024, 64, 1.0f);
  k_transpose_tile<<<dim3(16, 16, 1), 256, 0, stream>>>(Wp, Wpt, 1024, 1024, 1.0f);
  k_convert<<<4096, 256, 0, stream>>>(query,  Xqb);
  k_convert<<<4096, 256, 0, stream>>>(keys,   Xkb);
  k_convert<<<4096, 256, 0, stream>>>(values, Xvb);

  k_gemm<0><<<dim3(64, 16), 256, 0, stream>>>(Xqb, Xkb, Wqt, Qb, Kb, nullptr, nullptr, nullptr);
  k_gemm<1><<<dim3(64, 8),  256, 0, stream>>>(Xvb, nullptr, Wvt, Vtb, nullptr, nullptr, nullptr, nullptr);

  k_attn<<<dim3(64, 128), 256, 0, stream>>>(Qb, Kb, Vtb, attn_out, AO);

  k_gemm<2><<<dim3(64, 8),  256, 0, stream>>>(AO, nullptr, Wpt, nullptr, nullptr, P, bp, query);
  k_ln<<<2048, 256, 0, stream>>>(P, gamma, beta, y);
}